// Round 1
// baseline (323.077 us; speedup 1.0000x reference)
//
#include <hip/hip_runtime.h>
#include <hip/hip_bf16.h>

#define B_DIM 16
#define C_DIM 256
#define E_DIM 9216
#define K_DIM 4096

// ---------------------------------------------------------------------------
// Kernel 1: score[b,e] = sum_c x[b,c,e]^2, converted to a sortable uint key.
// Non-negative floats: key = bits | 0x80000000 is monotone. Invalid edges
// (e >= edges_count[b]) get key 0 (strictly below every valid key).
// Double accumulation: products of fp32 values are exact in double, so the
// rounded fp32 score is the correctly-rounded true score (minimizes
// disagreement with XLA's reduction order at top-K boundary).
// ---------------------------------------------------------------------------
__global__ __launch_bounds__(256) void score_kernel(
    const float* __restrict__ x, const void* __restrict__ ecp,
    unsigned* __restrict__ keys) {
  int tid = blockIdx.x * blockDim.x + threadIdx.x;  // 0 .. B*E-1
  int b = tid / E_DIM;
  int e = tid - b * E_DIM;

  // edges_count may be int32 or int64 (reference casts to int64; harness
  // convention says int32). Detect: counts are in [K, E] so for int64
  // little-endian layout the int32 view at odd positions is 0.
  const int* p32 = (const int*)ecp;
  long long cnt = (p32[1] == 0) ? ((const long long*)ecp)[b] : (long long)p32[b];

  const float* col = x + (size_t)b * C_DIM * E_DIM + e;
  double a0 = 0.0, a1 = 0.0, a2 = 0.0, a3 = 0.0;
#pragma unroll 8
  for (int c = 0; c < C_DIM; c += 4) {
    float v0 = col[(size_t)(c + 0) * E_DIM];
    float v1 = col[(size_t)(c + 1) * E_DIM];
    float v2 = col[(size_t)(c + 2) * E_DIM];
    float v3 = col[(size_t)(c + 3) * E_DIM];
    a0 += (double)v0 * v0;
    a1 += (double)v1 * v1;
    a2 += (double)v2 * v2;
    a3 += (double)v3 * v3;
  }
  float s = (float)((a0 + a1) + (a2 + a3));
  unsigned key = (e < cnt) ? (__float_as_uint(s) | 0x80000000u) : 0u;
  keys[tid] = key;
}

// ---------------------------------------------------------------------------
// Block-wide exclusive scan (512 threads = 8 waves) returning block total.
// Wave scan via shfl_up, cross-wave via LDS.
// ---------------------------------------------------------------------------
__device__ __forceinline__ void block_scan(int flag, int tid, int* wsum,
                                           int nwaves, int* excl, int* total) {
  int lane = tid & 63;
  int wid = tid >> 6;
  int v = flag;
#pragma unroll
  for (int i = 1; i < 64; i <<= 1) {
    int t = __shfl_up(v, i, 64);
    if (lane >= i) v += t;
  }
  if (lane == 63) wsum[wid] = v;
  __syncthreads();
  int base = 0, tot = 0;
  for (int w = 0; w < nwaves; w++) {
    int s = wsum[w];
    if (w < wid) base += s;
    tot += s;
  }
  *excl = base + v - flag;
  *total = tot;
  __syncthreads();  // wsum safe to reuse
}

// ---------------------------------------------------------------------------
// Kernel 2: one block per mesh. 4-pass MSB radix select over uint keys in LDS
// finds T = K-th largest key and need_eq = K - count(key > T). Then a
// sequential-chunk compaction emits, in ascending e order, all e with
// key > T plus the first need_eq e's with key == T — exactly
// sort(top_k(score, K).indices) with lax.top_k's lowest-index tie-break.
// ---------------------------------------------------------------------------
__global__ __launch_bounds__(512) void select_kernel(
    const unsigned* __restrict__ keys, int* __restrict__ keep) {
  __shared__ unsigned lkeys[E_DIM];
  __shared__ int hist[256];
  __shared__ int wsum[8];
  __shared__ unsigned sh_prefix;
  __shared__ int sh_remK;

  const int b = blockIdx.x;
  const int tid = threadIdx.x;
  const int bs = blockDim.x;  // 512

  for (int e = tid; e < E_DIM; e += bs) lkeys[e] = keys[b * E_DIM + e];
  __syncthreads();

  unsigned prefix = 0;
  int remK = K_DIM;
  for (int pass = 3; pass >= 0; pass--) {
    int shift = pass * 8;
    for (int i = tid; i < 256; i += bs) hist[i] = 0;
    __syncthreads();
    for (int e = tid; e < E_DIM; e += bs) {
      unsigned key = lkeys[e];
      bool cand = (pass == 3) || ((key >> (shift + 8)) == prefix);
      if (cand) atomicAdd(&hist[(key >> shift) & 255], 1);
    }
    __syncthreads();
    if (tid == 0) {
      int cum = 0;
      int bin = 255;
      for (; bin > 0; bin--) {
        if (cum + hist[bin] >= remK) break;
        cum += hist[bin];
      }
      sh_prefix = (prefix << 8) | (unsigned)bin;
      sh_remK = remK - cum;
    }
    __syncthreads();
    prefix = sh_prefix;
    remK = sh_remK;
  }

  const unsigned T = prefix;
  const int need_eq = remK;  // # of ==T elements to keep (earliest e first)

  int eq_base = 0, keep_base = 0;
  const int nwaves = bs >> 6;
  for (int base_e = 0; base_e < E_DIM; base_e += bs) {  // 18 exact chunks
    int e = base_e + tid;
    unsigned key = lkeys[e];
    int eq = (key == T) ? 1 : 0;
    int gt = (key > T) ? 1 : 0;
    int eq_excl, eq_tot;
    block_scan(eq, tid, wsum, nwaves, &eq_excl, &eq_tot);
    int kp = gt | (eq && (eq_base + eq_excl) < need_eq ? 1 : 0);
    int k_excl, k_tot;
    block_scan(kp, tid, wsum, nwaves, &k_excl, &k_tot);
    int pos = keep_base + k_excl;
    if (kp && pos < K_DIM) keep[b * K_DIM + pos] = e;
    eq_base += eq_tot;
    keep_base += k_tot;
  }
}

// ---------------------------------------------------------------------------
// Kernel 3: gather. Each thread produces 4 consecutive outputs (float4 store,
// int4 index load). Reads are ascending-index gathers served by L1/L2/L3
// (x is L3-resident after kernel 1).
// ---------------------------------------------------------------------------
__global__ __launch_bounds__(256) void gather_kernel(
    const float* __restrict__ x, const int* __restrict__ keep,
    float* __restrict__ out) {
  int tid = blockIdx.x * blockDim.x + threadIdx.x;  // over B*C*K/4
  const int KQ = K_DIM / 4;                         // 1024
  int q = tid & (KQ - 1);
  int bc = tid >> 10;  // b*C + c
  int b = bc >> 8;     // C = 256

  int4 idx4 = ((const int4*)(keep + b * K_DIM))[q];
  const float* row = x + (size_t)bc * E_DIM;
  float4 o;
  o.x = row[idx4.x];
  o.y = row[idx4.y];
  o.z = row[idx4.z];
  o.w = row[idx4.w];
  ((float4*)out)[tid] = o;
}

extern "C" void kernel_launch(void* const* d_in, const int* in_sizes, int n_in,
                              void* d_out, int out_size, void* d_ws,
                              size_t ws_size, hipStream_t stream) {
  const float* x = (const float*)d_in[0];
  const void* ec = d_in[1];
  float* out = (float*)d_out;

  unsigned* keys = (unsigned*)d_ws;                 // B*E uints (~2.3 MB)
  int* keep = (int*)(keys + (size_t)B_DIM * E_DIM); // B*K ints (~256 KB)

  score_kernel<<<(B_DIM * E_DIM) / 256, 256, 0, stream>>>(x, ec, keys);
  select_kernel<<<B_DIM, 512, 0, stream>>>(keys, keep);
  gather_kernel<<<(B_DIM * C_DIM * (K_DIM / 4)) / 256, 256, 0, stream>>>(
      x, keep, out);
}

// Round 2
// 285.329 us; speedup vs baseline: 1.1323x; 1.1323x over previous
//
#include <hip/hip_runtime.h>
#include <hip/hip_bf16.h>

#define B_DIM 16
#define C_DIM 256
#define E_DIM 9216
#define K_DIM 4096
#define SEL_T 512              // select block threads
#define EPT   (E_DIM / SEL_T)  // 18 keys per thread, contiguous

// ---------------------------------------------------------------------------
// Kernel 1: score[b,e] = sum_c x[b,c,e]^2 -> sortable uint key.
// Non-negative floats: bits | 0x80000000 is order-preserving. Invalid edges
// get key 0. Double accumulation => correctly-rounded fp32 score (immune to
// reduction-order differences vs XLA at the top-K boundary).
// float2: each thread produces 2 consecutive e (8 B/lane loads).
// ---------------------------------------------------------------------------
__global__ __launch_bounds__(256) void score_kernel(
    const float* __restrict__ x, const void* __restrict__ ecp,
    unsigned* __restrict__ keys) {
  int tid = blockIdx.x * blockDim.x + threadIdx.x;  // 0 .. B*E/2-1
  const int EH = E_DIM / 2;
  int b = tid / EH;
  int e = (tid - b * EH) * 2;

  const int* p32 = (const int*)ecp;
  long long cnt = (p32[1] == 0) ? ((const long long*)ecp)[b] : (long long)p32[b];

  const float* col = x + (size_t)b * C_DIM * E_DIM + e;
  double a00 = 0.0, a01 = 0.0, a10 = 0.0, a11 = 0.0;
#pragma unroll 8
  for (int c = 0; c < C_DIM; c += 2) {
    float2 v0 = *(const float2*)(col + (size_t)c * E_DIM);
    float2 v1 = *(const float2*)(col + (size_t)(c + 1) * E_DIM);
    a00 += (double)v0.x * v0.x;
    a10 += (double)v0.y * v0.y;
    a01 += (double)v1.x * v1.x;
    a11 += (double)v1.y * v1.y;
  }
  float s0 = (float)(a00 + a01);
  float s1 = (float)(a10 + a11);
  uint2 k;
  k.x = (e + 0 < cnt) ? (__float_as_uint(s0) | 0x80000000u) : 0u;
  k.y = (e + 1 < cnt) ? (__float_as_uint(s1) | 0x80000000u) : 0u;
  *(uint2*)(keys + (size_t)b * E_DIM + e) = k;
}

// ---------------------------------------------------------------------------
// Block-wide exclusive scan over SEL_T threads (8 waves). Returns excl + tot.
// ---------------------------------------------------------------------------
__device__ __forceinline__ void block_scan(int val, int tid, int* wsum,
                                           int* excl, int* total) {
  int lane = tid & 63;
  int wid = tid >> 6;
  int v = val;
#pragma unroll
  for (int i = 1; i < 64; i <<= 1) {
    int t = __shfl_up(v, i, 64);
    if (lane >= i) v += t;
  }
  if (lane == 63) wsum[wid] = v;
  __syncthreads();
  int base = 0, tot = 0;
#pragma unroll
  for (int w = 0; w < SEL_T / 64; w++) {
    int s = wsum[w];
    if (w < wid) base += s;
    tot += s;
  }
  *excl = base + v - val;
  *total = tot;
  __syncthreads();
}

// ---------------------------------------------------------------------------
// Kernel 2: one block per mesh. 4-pass MSB radix select.
//  - keys held in registers, EPT contiguous per thread
//  - histogram via ballot-match (one leader atomic per distinct byte per
//    wave -> no same-bin serialization even with clustered exponents)
//  - boundary bin found by parallel suffix-scan over 256 bins
//  - compaction with ONE packed block scan, emits ascending-e order:
//    all key>T plus first need_eq key==T  == sort(top_k(score,K).indices)
// ---------------------------------------------------------------------------
__global__ __launch_bounds__(SEL_T) void select_kernel(
    const unsigned* __restrict__ keys, int* __restrict__ keep) {
  __shared__ unsigned lkeys[E_DIM];
  __shared__ int hist[256];
  __shared__ int wsum[SEL_T / 64];
  __shared__ unsigned sh_prefix;
  __shared__ int sh_remK;

  const int b = blockIdx.x;
  const int tid = threadIdx.x;
  const int lane = tid & 63;

  // stage keys (coalesced uint2), then pull contiguous EPT into registers
  {
    const uint2* gk = (const uint2*)(keys + (size_t)b * E_DIM);
    uint2* lk2 = (uint2*)lkeys;
    for (int i = tid; i < E_DIM / 2; i += SEL_T) lk2[i] = gk[i];
  }
  __syncthreads();

  unsigned kreg[EPT];
  const int base_e = tid * EPT;
#pragma unroll
  for (int j = 0; j < EPT; j++) kreg[j] = lkeys[base_e + j];

  unsigned prefix = 0;
  int remK = K_DIM;
#pragma unroll
  for (int pass = 3; pass >= 0; pass--) {
    const int shift = pass * 8;
    if (tid < 256) hist[tid] = 0;
    __syncthreads();

    // ballot-match histogram
#pragma unroll
    for (int j = 0; j < EPT; j++) {
      unsigned key = kreg[j];
      bool cand = (pass == 3) || ((key >> (shift + 8)) == prefix);
      unsigned byte = (key >> shift) & 255u;
      unsigned long long m = __ballot(cand);
#pragma unroll
      for (int bit = 0; bit < 8; bit++) {
        unsigned long long bb = __ballot((byte >> bit) & 1u);
        m &= ((byte >> bit) & 1u) ? bb : ~bb;
      }
      if (cand) {
        int leader = __ffsll((unsigned long long)m) - 1;
        if (lane == leader) atomicAdd(&hist[byte], (int)__popcll(m));
      }
    }
    __syncthreads();

    // parallel suffix count: thread tid<256 handles bin u = 255-tid
    int h = 0;
    if (tid < 256) h = hist[255 - tid];
    int excl, tot;
    block_scan(h, tid, wsum, &excl, &tot);
    if (tid < 256) {
      int s_incl = excl + h;  // suffix[u] = sum of bins >= u
      if (s_incl >= remK && (s_incl - h) < remK) {
        sh_prefix = (prefix << 8) | (unsigned)(255 - tid);
        sh_remK = remK - (s_incl - h);
      }
    }
    __syncthreads();
    prefix = sh_prefix;
    remK = sh_remK;
  }

  const unsigned T = prefix;
  const int need_eq = remK;

  // compaction: one packed scan (gt<<16 | eq), then per-thread ordered emit
  int gt_cnt = 0, eq_cnt = 0;
#pragma unroll
  for (int j = 0; j < EPT; j++) {
    gt_cnt += (kreg[j] > T);
    eq_cnt += (kreg[j] == T);
  }
  int excl, tot;
  block_scan((gt_cnt << 16) | eq_cnt, tid, wsum, &excl, &tot);
  int gt_b = excl >> 16;
  int eq_b = excl & 0xFFFF;

  int* kout = keep + b * K_DIM;
#pragma unroll
  for (int j = 0; j < EPT; j++) {
    unsigned key = kreg[j];
    if (key > T) {
      int pos = gt_b + (eq_b < need_eq ? eq_b : need_eq);
      kout[pos] = base_e + j;
      gt_b++;
    } else if (key == T) {
      if (eq_b < need_eq) kout[gt_b + eq_b] = base_e + j;
      eq_b++;
    }
  }
}

// ---------------------------------------------------------------------------
// Kernel 3: gather. 4 outputs per thread (float4 store, int4 index load).
// Ascending indices -> high L1/L2/L3 locality on the reads.
// ---------------------------------------------------------------------------
__global__ __launch_bounds__(256) void gather_kernel(
    const float* __restrict__ x, const int* __restrict__ keep,
    float* __restrict__ out) {
  int tid = blockIdx.x * blockDim.x + threadIdx.x;  // over B*C*K/4
  const int KQ = K_DIM / 4;  // 1024
  int q = tid & (KQ - 1);
  int bc = tid >> 10;  // b*C + c
  int b = bc >> 8;     // C = 256

  int4 idx4 = ((const int4*)(keep + b * K_DIM))[q];
  const float* row = x + (size_t)bc * E_DIM;
  float4 o;
  o.x = row[idx4.x];
  o.y = row[idx4.y];
  o.z = row[idx4.z];
  o.w = row[idx4.w];
  ((float4*)out)[tid] = o;
}

extern "C" void kernel_launch(void* const* d_in, const int* in_sizes, int n_in,
                              void* d_out, int out_size, void* d_ws,
                              size_t ws_size, hipStream_t stream) {
  const float* x = (const float*)d_in[0];
  const void* ec = d_in[1];
  float* out = (float*)d_out;

  unsigned* keys = (unsigned*)d_ws;                  // B*E uints (~590 KB)
  int* keep = (int*)(keys + (size_t)B_DIM * E_DIM);  // B*K ints (~256 KB)

  score_kernel<<<(B_DIM * E_DIM / 2) / 256, 256, 0, stream>>>(x, ec, keys);
  select_kernel<<<B_DIM, SEL_T, 0, stream>>>(keys, keep);
  gather_kernel<<<(B_DIM * C_DIM * (K_DIM / 4)) / 256, 256, 0, stream>>>(
      x, keep, out);
}

// Round 3
// 279.522 us; speedup vs baseline: 1.1558x; 1.0208x over previous
//
#include <hip/hip_runtime.h>
#include <hip/hip_bf16.h>

#define B_DIM 16
#define C_DIM 256
#define E_DIM 9216
#define K_DIM 4096
#define SEL_T 512              // select block threads
#define EPT   (E_DIM / SEL_T)  // 18 keys per thread, contiguous

typedef float v4f __attribute__((ext_vector_type(4)));

// ---------------------------------------------------------------------------
// Kernel 1: score[b,e] = sum_c x[b,c,e]^2 -> sortable uint key.
// Non-negative floats: bits | 0x80000000 is order-preserving. Invalid edges
// get key 0. Double accumulation => correctly-rounded fp32 score (immune to
// reduction-order differences vs XLA at the top-K boundary).
//
// Launch geometry: 1 edge/thread, 64-thread blocks, B*E/64 = 2304 blocks
// = exactly 9 waves per CU on 256 CUs -> no tail imbalance (the previous
// 288x256 grid left 224 CUs idle for half the kernel). HBM-bound: ~151 MB
// read at ~6 TB/s ~= 26 us.
// ---------------------------------------------------------------------------
__global__ __launch_bounds__(64) void score_kernel(
    const float* __restrict__ x, const void* __restrict__ ecp,
    unsigned* __restrict__ keys) {
  int tid = blockIdx.x * 64 + threadIdx.x;  // 0 .. B*E-1
  int b = tid / E_DIM;
  int e = tid - b * E_DIM;

  // edges_count dtype sniff: counts are in [K, E] (fit in 16 bits), so an
  // int64 little-endian layout has zero at odd int32 positions.
  const int* p32 = (const int*)ecp;
  long long cnt = (p32[1] == 0) ? ((const long long*)ecp)[b] : (long long)p32[b];

  const float* col = x + (size_t)b * C_DIM * E_DIM + e;
  double a0 = 0.0, a1 = 0.0, a2 = 0.0, a3 = 0.0;
#pragma unroll 8
  for (int c = 0; c < C_DIM; c += 4) {
    float v0 = col[(size_t)(c + 0) * E_DIM];
    float v1 = col[(size_t)(c + 1) * E_DIM];
    float v2 = col[(size_t)(c + 2) * E_DIM];
    float v3 = col[(size_t)(c + 3) * E_DIM];
    a0 += (double)v0 * v0;
    a1 += (double)v1 * v1;
    a2 += (double)v2 * v2;
    a3 += (double)v3 * v3;
  }
  float s = (float)((a0 + a1) + (a2 + a3));
  keys[tid] = (e < cnt) ? (__float_as_uint(s) | 0x80000000u) : 0u;
}

// ---------------------------------------------------------------------------
// Block-wide exclusive scan over SEL_T threads (8 waves). Returns excl + tot.
// ---------------------------------------------------------------------------
__device__ __forceinline__ void block_scan(int val, int tid, int* wsum,
                                           int* excl, int* total) {
  int lane = tid & 63;
  int wid = tid >> 6;
  int v = val;
#pragma unroll
  for (int i = 1; i < 64; i <<= 1) {
    int t = __shfl_up(v, i, 64);
    if (lane >= i) v += t;
  }
  if (lane == 63) wsum[wid] = v;
  __syncthreads();
  int base = 0, tot = 0;
#pragma unroll
  for (int w = 0; w < SEL_T / 64; w++) {
    int s = wsum[w];
    if (w < wid) base += s;
    tot += s;
  }
  *excl = base + v - val;
  *total = tot;
  __syncthreads();
}

// ---------------------------------------------------------------------------
// Kernel 2: one block per mesh. 4-pass MSB radix select.
//  - keys held in registers, EPT contiguous per thread
//  - histogram via ballot-match (one leader atomic per distinct byte per
//    wave -> no same-bin serialization even with clustered exponents)
//  - boundary bin found by parallel suffix-scan over 256 bins
//  - compaction with ONE packed block scan, emits ascending-e order:
//    all key>T plus first need_eq key==T  == sort(top_k(score,K).indices)
// ---------------------------------------------------------------------------
__global__ __launch_bounds__(SEL_T) void select_kernel(
    const unsigned* __restrict__ keys, int* __restrict__ keep) {
  __shared__ unsigned lkeys[E_DIM];
  __shared__ int hist[256];
  __shared__ int wsum[SEL_T / 64];
  __shared__ unsigned sh_prefix;
  __shared__ int sh_remK;

  const int b = blockIdx.x;
  const int tid = threadIdx.x;
  const int lane = tid & 63;

  // stage keys (coalesced uint2), then pull contiguous EPT into registers
  {
    const uint2* gk = (const uint2*)(keys + (size_t)b * E_DIM);
    uint2* lk2 = (uint2*)lkeys;
    for (int i = tid; i < E_DIM / 2; i += SEL_T) lk2[i] = gk[i];
  }
  __syncthreads();

  unsigned kreg[EPT];
  const int base_e = tid * EPT;
#pragma unroll
  for (int j = 0; j < EPT; j++) kreg[j] = lkeys[base_e + j];

  unsigned prefix = 0;
  int remK = K_DIM;
#pragma unroll
  for (int pass = 3; pass >= 0; pass--) {
    const int shift = pass * 8;
    if (tid < 256) hist[tid] = 0;
    __syncthreads();

    // ballot-match histogram
#pragma unroll
    for (int j = 0; j < EPT; j++) {
      unsigned key = kreg[j];
      bool cand = (pass == 3) || ((key >> (shift + 8)) == prefix);
      unsigned byte = (key >> shift) & 255u;
      unsigned long long m = __ballot(cand);
#pragma unroll
      for (int bit = 0; bit < 8; bit++) {
        unsigned long long bb = __ballot((byte >> bit) & 1u);
        m &= ((byte >> bit) & 1u) ? bb : ~bb;
      }
      if (cand) {
        int leader = __ffsll((unsigned long long)m) - 1;
        if (lane == leader) atomicAdd(&hist[byte], (int)__popcll(m));
      }
    }
    __syncthreads();

    // parallel suffix count: thread tid<256 handles bin u = 255-tid
    int h = 0;
    if (tid < 256) h = hist[255 - tid];
    int excl, tot;
    block_scan(h, tid, wsum, &excl, &tot);
    if (tid < 256) {
      int s_incl = excl + h;  // suffix[u] = sum of bins >= u
      if (s_incl >= remK && (s_incl - h) < remK) {
        sh_prefix = (prefix << 8) | (unsigned)(255 - tid);
        sh_remK = remK - (s_incl - h);
      }
    }
    __syncthreads();
    prefix = sh_prefix;
    remK = sh_remK;
  }

  const unsigned T = prefix;
  const int need_eq = remK;

  // compaction: one packed scan (gt<<16 | eq), then per-thread ordered emit
  int gt_cnt = 0, eq_cnt = 0;
#pragma unroll
  for (int j = 0; j < EPT; j++) {
    gt_cnt += (kreg[j] > T);
    eq_cnt += (kreg[j] == T);
  }
  int excl, tot;
  block_scan((gt_cnt << 16) | eq_cnt, tid, wsum, &excl, &tot);
  int gt_b = excl >> 16;
  int eq_b = excl & 0xFFFF;

  int* kout = keep + b * K_DIM;
#pragma unroll
  for (int j = 0; j < EPT; j++) {
    unsigned key = kreg[j];
    if (key > T) {
      int pos = gt_b + (eq_b < need_eq ? eq_b : need_eq);
      kout[pos] = base_e + j;
      gt_b++;
    } else if (key == T) {
      if (eq_b < need_eq) kout[gt_b + eq_b] = base_e + j;
      eq_b++;
    }
  }
}

// ---------------------------------------------------------------------------
// Kernel 3: gather. 4 outputs per thread (float4 store, int4 index load).
// Ascending indices -> high L1/L2/L3 locality on the reads. The 64 MB output
// is never re-read: non-temporal stores keep it from evicting x (151 MB)
// from the 256 MB Infinity Cache, so gather reads stay L3-served.
// ---------------------------------------------------------------------------
__global__ __launch_bounds__(256) void gather_kernel(
    const float* __restrict__ x, const int* __restrict__ keep,
    float* __restrict__ out) {
  int tid = blockIdx.x * blockDim.x + threadIdx.x;  // over B*C*K/4
  const int KQ = K_DIM / 4;  // 1024
  int q = tid & (KQ - 1);
  int bc = tid >> 10;  // b*C + c
  int b = bc >> 8;     // C = 256

  int4 idx4 = ((const int4*)(keep + b * K_DIM))[q];
  const float* row = x + (size_t)bc * E_DIM;
  v4f o;
  o.x = row[idx4.x];
  o.y = row[idx4.y];
  o.z = row[idx4.z];
  o.w = row[idx4.w];
  __builtin_nontemporal_store(o, (v4f*)out + tid);
}

extern "C" void kernel_launch(void* const* d_in, const int* in_sizes, int n_in,
                              void* d_out, int out_size, void* d_ws,
                              size_t ws_size, hipStream_t stream) {
  const float* x = (const float*)d_in[0];
  const void* ec = d_in[1];
  float* out = (float*)d_out;

  unsigned* keys = (unsigned*)d_ws;                  // B*E uints (~590 KB)
  int* keep = (int*)(keys + (size_t)B_DIM * E_DIM);  // B*K ints (~256 KB)

  score_kernel<<<(B_DIM * E_DIM) / 64, 64, 0, stream>>>(x, ec, keys);
  select_kernel<<<B_DIM, SEL_T, 0, stream>>>(keys, keep);
  gather_kernel<<<(B_DIM * C_DIM * (K_DIM / 4)) / 256, 256, 0, stream>>>(
      x, keep, out);
}